// Round 4
// baseline (230.575 us; speedup 1.0000x reference)
//
#include <hip/hip_runtime.h>

#define NB 256
#define NP 512
#define NE 256
#define NH 128
#define PT 32              // pool rows per tile
#define HALF 256           // pool rows per block (P split across 2 blocks)
#define NT (HALF / PT)     // 8 tiles per block

typedef __attribute__((ext_vector_type(8))) short bf16x8;
typedef __attribute__((ext_vector_type(4))) float f32x4;

__device__ __forceinline__ short f2bf(float f) {
  union { float f; unsigned u; } v; v.f = f;
  unsigned r = v.u + 0x7fffu + ((v.u >> 16) & 1u);   // RNE
  return (short)(r >> 16);
}
__device__ __forceinline__ float bf2f(short s) {
  union { unsigned u; float f; } v;
  v.u = ((unsigned)(unsigned short)s) << 16;
  return v.f;
}
// tanh(x) = 1 - 2/(exp2(2*log2e*x)+1)
__device__ __forceinline__ float fast_tanh(float x) {
  float u = __builtin_amdgcn_exp2f(x * 2.8853900817779268f);
  return 1.0f - 2.0f * __builtin_amdgcn_rcpf(u + 1.0f);
}

union SMem {
  struct {
    short buf[3][PT * NE];   // 3 x 16 KB bf16 tiles (XOR-swizzled rows)
    float sp[2][4][33];      // double-buffered score partials [sb][ht][p]
    float zsh;               // block Z broadcast
  } s;
  float pool[16][NE];        // epilogue pooled partials (aliases buf[0])
};

// One block per (b, half-of-P). Fused cross-block combine via atomic flag.
__global__ __launch_bounds__(512, 4) void pathattn_part(
    const float* __restrict__ x, const float* __restrict__ w1,
    const float* __restrict__ w2, float* __restrict__ wsPool,
    float* __restrict__ wsZ, int* __restrict__ flags,
    float* __restrict__ out) {
  __shared__ SMem sm;
  __shared__ int lastflag;

  const int tid  = threadIdx.x;
  const int lane = tid & 63;
  const int wid  = tid >> 6;           // 0..7
  const int n15  = lane & 15;
  const int l4   = lane >> 4;          // 0..3
  const int ht   = wid & 3;            // h-tile: h in [ht*32, ht*32+32)
  const int ph   = wid >> 2;           // p-slice: p in [ph*16, ph*16+16)
  const int b    = blockIdx.x >> 1;
  const int half = blockIdx.x & 1;
  const float* xb = x + (size_t)b * NP * NE + (size_t)half * HALF * NE;

  // ---- A-fragments (w1, 32 h x 256 k per wave) + w2 values ----
  bf16x8 afrag[2][8];
  float w2v[2][4];
  #pragma unroll
  for (int sub = 0; sub < 2; ++sub) {
    const int h = ht * 32 + sub * 16 + n15;
    #pragma unroll
    for (int kt = 0; kt < 8; ++kt) {
      const f32x4* s0 = (const f32x4*)(w1 + h * NE + kt * 32 + l4 * 8);
      f32x4 a = s0[0], c = s0[1];
      bf16x8 v;
      v[0]=f2bf(a[0]); v[1]=f2bf(a[1]); v[2]=f2bf(a[2]); v[3]=f2bf(a[3]);
      v[4]=f2bf(c[0]); v[5]=f2bf(c[1]); v[6]=f2bf(c[2]); v[7]=f2bf(c[3]);
      afrag[sub][kt] = v;
    }
    #pragma unroll
    for (int r = 0; r < 4; ++r)
      w2v[sub][r] = w2[ht * 32 + sub * 16 + l4 * 4 + r];
  }

  // ---- staging: thread owns row srow, 2 LDS 16B-chunks; XOR-swizzled source ----
  const int srow = tid >> 4;           // 0..31
  const int ssub = tid & 15;           // chunk pair index
  f32x4 streg[4];
  auto issue_loads = [&](int t) {
    const float* base = xb + (size_t)t * PT * NE + srow * NE;
    #pragma unroll
    for (int j = 0; j < 2; ++j) {
      const int cg = (ssub * 2 + j) ^ (srow & 7);   // global chunk for LDS chunk cs
      streg[j*2]   = *(const f32x4*)(base + cg * 8);
      streg[j*2+1] = *(const f32x4*)(base + cg * 8 + 4);
    }
  };
  auto write_tile = [&](int bi) {
    short* dst = sm.s.buf[bi] + srow * NE;
    #pragma unroll
    for (int j = 0; j < 2; ++j) {
      const int cs = ssub * 2 + j;
      bf16x8 v;
      v[0]=f2bf(streg[j*2][0]);   v[1]=f2bf(streg[j*2][1]);
      v[2]=f2bf(streg[j*2][2]);   v[3]=f2bf(streg[j*2][3]);
      v[4]=f2bf(streg[j*2+1][0]); v[5]=f2bf(streg[j*2+1][1]);
      v[6]=f2bf(streg[j*2+1][2]); v[7]=f2bf(streg[j*2+1][3]);
      *(bf16x8*)(dst + cs * 8) = v;
    }
  };

  // ---- MFMA phase: D[h][p] = w1 . x^T for this wave's 32h x 16p ----
  const int pcol = ph * 16 + n15;      // this lane's p (B-frag col)
  const int px7  = pcol & 7;
  auto mfma_phase = [&](int t) {
    const short* bufc = sm.s.buf[t % 3] + pcol * NE;
    f32x4 acc0 = {0.f,0.f,0.f,0.f}, acc1 = {0.f,0.f,0.f,0.f};
    #pragma unroll
    for (int kt = 0; kt < 8; ++kt) {
      const int cc = (kt * 4 + l4) ^ px7;           // swizzled chunk
      bf16x8 bv = *(const bf16x8*)(bufc + cc * 8);
      acc0 = __builtin_amdgcn_mfma_f32_16x16x32_bf16(afrag[0][kt], bv, acc0, 0, 0, 0);
      acc1 = __builtin_amdgcn_mfma_f32_16x16x32_bf16(afrag[1][kt], bv, acc1, 0, 0, 0);
    }
    float s = 0.f;
    #pragma unroll
    for (int r = 0; r < 4; ++r)
      s += fast_tanh(acc0[r]) * w2v[0][r] + fast_tanh(acc1[r]) * w2v[1][r];
    s += __shfl_xor(s, 16, 64);
    s += __shfl_xor(s, 32, 64);
    if (l4 == 0) sm.s.sp[t & 1][ht][pcol] = s;
  };

  // ---- exp + pooling for tile t ----
  f32x4 pacc0 = {0.f,0.f,0.f,0.f}, pacc1 = {0.f,0.f,0.f,0.f};
  float zacc = 0.f;
  const int prow0 = tid >> 5;          // 0..15
  const int chunk = tid & 31;          // e-chunk (8 e's)
  auto exp_pool = [&](int t) {
    const int sb = t & 1;
    const short* bufc = sm.s.buf[t % 3];
    const int p = lane & 31;
    float ssum = sm.s.sp[sb][0][p] + sm.s.sp[sb][1][p] +
                 sm.s.sp[sb][2][p] + sm.s.sp[sb][3][p];
    float e = __builtin_amdgcn_exp2f(ssum * 1.4426950408889634f);
    zacc += e;                          // duplicated across waves; wave0 used
    #pragma unroll
    for (int it = 0; it < 2; ++it) {
      const int r = prow0 + it * 16;
      float ep = __shfl(e, r | (lane & 32), 64);
      const int cc = chunk ^ (r & 7);
      bf16x8 v = *(const bf16x8*)(bufc + r * NE + cc * 8);
      pacc0[0] += ep * bf2f(v[0]); pacc0[1] += ep * bf2f(v[1]);
      pacc0[2] += ep * bf2f(v[2]); pacc0[3] += ep * bf2f(v[3]);
      pacc1[0] += ep * bf2f(v[4]); pacc1[1] += ep * bf2f(v[5]);
      pacc1[2] += ep * bf2f(v[6]); pacc1[3] += ep * bf2f(v[7]);
    }
  };

  // ---- pipeline: 1 barrier per iteration, 3 LDS buffers ----
  issue_loads(0);
  write_tile(0);
  issue_loads(1);
  __syncthreads();
  for (int t = 0; t < NT; ++t) {
    mfma_phase(t);
    if (t + 1 < NT) write_tile((t + 1) % 3);
    if (t + 2 < NT) issue_loads(t + 2);
    if (t >= 1) exp_pool(t - 1);
    __syncthreads();
  }
  exp_pool(NT - 1);
  __syncthreads();

  // ---- epilogue: reduce pacc across the 16 row-groups (pool aliases buf[0]) ----
  *(f32x4*)(&sm.pool[prow0][chunk * 8])     = pacc0;
  *(f32x4*)(&sm.pool[prow0][chunk * 8 + 4]) = pacc1;
  if (wid == 0) {
    float z = zacc;
    #pragma unroll
    for (int m = 1; m <= 16; m <<= 1) z += __shfl_xor(z, m, 64);
    if (lane == 0) sm.s.zsh = z;
  }
  __syncthreads();

  float v = 0.f;
  const float z = sm.s.zsh;
  if (tid < NE) {
    #pragma unroll
    for (int g = 0; g < 16; ++g) v += sm.pool[g][tid];
    wsPool[(size_t)blockIdx.x * NE + tid] = v;
    if (tid == 0) wsZ[blockIdx.x] = z;
  }
  __threadfence();          // release our partial to device scope
  __syncthreads();
  if (tid == 0) lastflag = atomicAdd(&flags[b], 1);
  __syncthreads();
  if (lastflag == 1 && tid < NE) {     // we are the second (combining) block
    __threadfence();        // acquire partner's stores
    const int partner = (int)blockIdx.x ^ 1;
    float pv = wsPool[(size_t)partner * NE + tid];
    float pz = wsZ[partner];
    out[(size_t)b * NE + tid] = (v + pv) / (z + pz);
  }
}

extern "C" void kernel_launch(void* const* d_in, const int* in_sizes, int n_in,
                              void* d_out, int out_size, void* d_ws, size_t ws_size,
                              hipStream_t stream) {
  (void)in_sizes; (void)n_in; (void)out_size; (void)ws_size;
  const float* x  = (const float*)d_in[0];
  const float* w1 = (const float*)d_in[1];
  const float* w2 = (const float*)d_in[2];
  float* out = (float*)d_out;
  float* wsPool = (float*)d_ws;                  // [512][256] f32
  float* wsZ    = wsPool + 512 * NE;             // [512] f32
  int*   flags  = (int*)(wsZ + 512);             // [256] int
  hipMemsetAsync(flags, 0, NB * sizeof(int), stream);
  pathattn_part<<<2 * NB, 512, 0, stream>>>(x, w1, w2, wsPool, wsZ, flags, out);
}

// Round 5
// 60.713 us; speedup vs baseline: 3.7978x; 3.7978x over previous
//
#include <hip/hip_runtime.h>

#define NB 256
#define NP 512
#define NE 256
#define NH 128
#define PT 16              // pool rows per tile
#define QP 128             // pool rows per block (P split across 4 blocks)
#define NT (QP / PT)       // 8 tiles per block

typedef __attribute__((ext_vector_type(8))) short bf16x8;
typedef __attribute__((ext_vector_type(4))) float f32x4;

__device__ __forceinline__ short f2bf(float f) {
  union { float f; unsigned u; } v; v.f = f;
  unsigned r = v.u + 0x7fffu + ((v.u >> 16) & 1u);   // RNE
  return (short)(r >> 16);
}
__device__ __forceinline__ float bf2f(short s) {
  union { unsigned u; float f; } v;
  v.u = ((unsigned)(unsigned short)s) << 16;
  return v.f;
}
// tanh(x) = 1 - 2/(exp2(2*log2e*x)+1)
__device__ __forceinline__ float fast_tanh(float x) {
  float u = __builtin_amdgcn_exp2f(x * 2.8853900817779268f);
  return 1.0f - 2.0f * __builtin_amdgcn_rcpf(u + 1.0f);
}

union SMem {
  struct {
    short buf[2][PT * NE];   // 2 x 8 KB bf16 tiles (XOR-swizzled chunks)
    float sp[2][4][20];      // double-buffered score partials [sb][wave][p]
  } s;
  float pool[8][NE];         // epilogue pooled partials (aliases buf[0], 8 KB)
};

// One block per (b, quarter-of-P). 256 threads = 4 waves.
__global__ __attribute__((amdgpu_flat_work_group_size(256, 256)))
           __attribute__((amdgpu_waves_per_eu(4, 4)))
void pathattn_part(const float* __restrict__ x, const float* __restrict__ w1,
                   const float* __restrict__ w2, float* __restrict__ wsPool,
                   float* __restrict__ wsZ) {
  __shared__ SMem sm;

  const int tid  = threadIdx.x;
  const int lane = tid & 63;
  const int wid  = tid >> 6;           // 0..3 — wave owns h-tiles {2*wid, 2*wid+1}
  const int n15  = lane & 15;
  const int l4   = lane >> 4;          // 0..3
  const int b    = blockIdx.x >> 2;
  const int quarter = blockIdx.x & 3;
  const float* xb = x + (size_t)b * NP * NE + (size_t)quarter * QP * NE;

  // ---- A-fragments (w1, 32 h per wave) + w2 values ----
  bf16x8 afrag[2][8];
  float w2v[2][4];
  #pragma unroll
  for (int sub = 0; sub < 2; ++sub) {
    const int h = (wid * 2 + sub) * 16 + n15;
    #pragma unroll
    for (int kt = 0; kt < 8; ++kt) {
      const f32x4* s0 = (const f32x4*)(w1 + h * NE + kt * 32 + l4 * 8);
      f32x4 a = s0[0], c = s0[1];
      bf16x8 v;
      v[0]=f2bf(a[0]); v[1]=f2bf(a[1]); v[2]=f2bf(a[2]); v[3]=f2bf(a[3]);
      v[4]=f2bf(c[0]); v[5]=f2bf(c[1]); v[6]=f2bf(c[2]); v[7]=f2bf(c[3]);
      afrag[sub][kt] = v;
    }
    #pragma unroll
    for (int r = 0; r < 4; ++r)
      w2v[sub][r] = w2[(wid * 2 + sub) * 16 + l4 * 4 + r];
  }

  // ---- staging: thread owns row srow, 2 LDS 16B-chunks; source-side swizzle ----
  const int srow = tid >> 4;           // 0..15
  const int scol = tid & 15;
  f32x4 streg[4];
  auto issue_loads = [&](int t) {
    const float* base = xb + (size_t)t * PT * NE + srow * NE;
    #pragma unroll
    for (int j = 0; j < 2; ++j) {
      const int cg = (scol + j * 16) ^ (srow & 7);  // global chunk for LDS chunk cs
      streg[j*2]   = *(const f32x4*)(base + cg * 8);
      streg[j*2+1] = *(const f32x4*)(base + cg * 8 + 4);
    }
  };
  auto write_tile = [&](int bi) {
    short* dst = sm.s.buf[bi] + srow * NE;
    #pragma unroll
    for (int j = 0; j < 2; ++j) {
      const int cs = scol + j * 16;                 // consecutive threads -> consecutive chunks
      bf16x8 v;
      v[0]=f2bf(streg[j*2][0]);   v[1]=f2bf(streg[j*2][1]);
      v[2]=f2bf(streg[j*2][2]);   v[3]=f2bf(streg[j*2][3]);
      v[4]=f2bf(streg[j*2+1][0]); v[5]=f2bf(streg[j*2+1][1]);
      v[6]=f2bf(streg[j*2+1][2]); v[7]=f2bf(streg[j*2+1][3]);
      *(bf16x8*)(dst + cs * 8) = v;
    }
  };

  // ---- MFMA phase: D[h][p] = w1 . x^T, wave's 32h x 16p ----
  const int px7 = n15 & 7;
  auto mfma_sp = [&](int t) {
    const short* bufc = sm.s.buf[t & 1] + n15 * NE;     // lane's p-row
    f32x4 acc0 = {0.f,0.f,0.f,0.f}, acc1 = {0.f,0.f,0.f,0.f};
    #pragma unroll
    for (int kt = 0; kt < 8; ++kt) {
      const int cc = (kt * 4 + l4) ^ px7;               // de-swizzled chunk
      bf16x8 bv = *(const bf16x8*)(bufc + cc * 8);
      acc0 = __builtin_amdgcn_mfma_f32_16x16x32_bf16(afrag[0][kt], bv, acc0, 0, 0, 0);
      acc1 = __builtin_amdgcn_mfma_f32_16x16x32_bf16(afrag[1][kt], bv, acc1, 0, 0, 0);
    }
    float s = 0.f;
    #pragma unroll
    for (int r = 0; r < 4; ++r)
      s += fast_tanh(acc0[r]) * w2v[0][r] + fast_tanh(acc1[r]) * w2v[1][r];
    s += __shfl_xor(s, 16, 64);
    s += __shfl_xor(s, 32, 64);
    if (l4 == 0) sm.s.sp[t & 1][wid][n15] = s;
  };

  // ---- exp + pooling ----
  f32x4 pacc0 = {0.f,0.f,0.f,0.f}, pacc1 = {0.f,0.f,0.f,0.f};
  float zacc = 0.f;
  const int prow  = (tid >> 5) & 7;    // 0..7: rows {prow, prow+8}
  const int chunk = tid & 31;          // e-chunk (8 e's)
  auto exp_pool = [&](int t) {
    const int sb = t & 1;
    const short* bufc = sm.s.buf[sb];
    float ssum = sm.s.sp[sb][0][n15] + sm.s.sp[sb][1][n15] +
                 sm.s.sp[sb][2][n15] + sm.s.sp[sb][3][n15];
    float e = __builtin_amdgcn_exp2f(ssum * 1.4426950408889634f);
    zacc += e;                          // per-lane partial for p = lane&15
    #pragma unroll
    for (int it = 0; it < 2; ++it) {
      const int r = prow + it * 8;
      float ep = __shfl(e, (lane & 48) | r, 64);        // lane holding p=r
      const int cc = chunk ^ (r & 7);
      bf16x8 v = *(const bf16x8*)(bufc + r * NE + cc * 8);
      pacc0[0] += ep * bf2f(v[0]); pacc0[1] += ep * bf2f(v[1]);
      pacc0[2] += ep * bf2f(v[2]); pacc0[3] += ep * bf2f(v[3]);
      pacc1[0] += ep * bf2f(v[4]); pacc1[1] += ep * bf2f(v[5]);
      pacc1[2] += ep * bf2f(v[6]); pacc1[3] += ep * bf2f(v[7]);
    }
  };

  // ---- pipeline: double buffer, 2 barriers/tile ----
  issue_loads(0);
  write_tile(0);
  __syncthreads();
  for (int t = 0; t < NT; ++t) {
    if (t + 1 < NT) issue_loads(t + 1);   // in flight across MFMA phase
    mfma_sp(t);
    __syncthreads();                      // B1: sp visible
    exp_pool(t);
    if (t + 1 < NT) write_tile((t + 1) & 1);
    __syncthreads();                      // B2: next buffer ready / reads done
  }

  // ---- epilogue (pool aliases buf[0]; all buf reads done after last B2) ----
  *(f32x4*)(&sm.pool[prow][chunk * 8])     = pacc0;
  *(f32x4*)(&sm.pool[prow][chunk * 8 + 4]) = pacc1;
  if (wid == 0) {
    float z = zacc;
    z += __shfl_xor(z, 1, 64);
    z += __shfl_xor(z, 2, 64);
    z += __shfl_xor(z, 4, 64);
    z += __shfl_xor(z, 8, 64);           // lanes 0..15 hold Z
    if (lane == 0) wsZ[blockIdx.x] = z;
  }
  __syncthreads();
  float v = 0.f;
  #pragma unroll
  for (int g = 0; g < 8; ++g) v += sm.pool[g][tid];
  wsPool[(size_t)blockIdx.x * NE + tid] = v;
}

// Combine the four P-quarters and normalize.
__global__ void pathattn_combine(const float* __restrict__ wsPool,
                                 const float* __restrict__ wsZ,
                                 float* __restrict__ out) {
  const int b = blockIdx.x, e = threadIdx.x;
  float v = 0.f, z = 0.f;
  #pragma unroll
  for (int q = 0; q < 4; ++q) {
    v += wsPool[(size_t)(4 * b + q) * NE + e];
    z += wsZ[4 * b + q];
  }
  out[(size_t)b * NE + e] = v / z;
}

extern "C" void kernel_launch(void* const* d_in, const int* in_sizes, int n_in,
                              void* d_out, int out_size, void* d_ws, size_t ws_size,
                              hipStream_t stream) {
  (void)in_sizes; (void)n_in; (void)out_size; (void)ws_size;
  const float* x  = (const float*)d_in[0];
  const float* w1 = (const float*)d_in[1];
  const float* w2 = (const float*)d_in[2];
  float* out = (float*)d_out;
  float* wsPool = (float*)d_ws;                  // [1024][256] f32
  float* wsZ    = wsPool + 1024 * NE;            // [1024] f32
  pathattn_part<<<4 * NB, 256, 0, stream>>>(x, w1, w2, wsPool, wsZ);
  pathattn_combine<<<NB, NE, 0, stream>>>(wsPool, wsZ, out);
}